// Round 7
// baseline (27050.797 us; speedup 1.0000x reference)
//
#include <hip/hip_runtime.h>
#include <hip/hip_bf16.h>
#include <stdint.h>

#define B_   128
#define S_   512
#define C_   256
#define DG_  256

// d_out offsets (fp32 elements): outs, pi, sigma, mu, mask
#define OFF_PI   262144
#define OFF_SIG  917504
#define OFF_MU   3538944
#define OFF_MASK 6160384

typedef __hip_bfloat16 bf16;
typedef __bf16 bf16x8 __attribute__((ext_vector_type(8)));
typedef float  f32x4  __attribute__((ext_vector_type(4)));

// ---- weight staging in device globals (zero d_ws dependence) ----
__device__ __align__(16) bf16  gWmain[768*256];   // Wih0[:, :256]
__device__ __align__(16) bf16  gWHH0 [768*256];
__device__ __align__(16) bf16  gWIH1 [768*256];
__device__ __align__(16) bf16  gWHH1 [768*256];
__device__ __align__(16) bf16  gWcat [96*512];    // [W_pi; W_sigma; W_mu; 0]
__device__ __align__(16) float gWtail[768*4];     // Wih0[:, 256:260] fp32
__device__ __align__(16) float gSm   [3200];      // small params fp32

// gSm offsets
#define SM_WPRE 0
#define SM_BPRE 16
#define SM_BIH0 20
#define SM_BHH0 788
#define SM_BIH1 1556
#define SM_BHH1 2324
#define SM_BPI  3092
#define SM_BSIG 3102
#define SM_BMU  3142

__device__ __forceinline__ bf16  f2b(float x){ return __float2bfloat16(x); }
__device__ __forceinline__ float sigm(float x){ return 1.f/(1.f + __expf(-x)); }
__device__ __forceinline__ float tanhfast(float x){ return 1.f - 2.f/(__expf(2.f*x) + 1.f); }
__device__ __forceinline__ f32x4 mfma16(bf16x8 a, bf16x8 b, f32x4 c){
    return __builtin_amdgcn_mfma_f32_16x16x32_bf16(a, b, c, 0, 0, 0);
}
// fp32 -> 8 bf16 fragment
__device__ __forceinline__ bf16x8 cvt8(const float* f){
    float4 a = *reinterpret_cast<const float4*>(f);
    float4 c = *reinterpret_cast<const float4*>(f + 4);
    bf16 o[8] = { f2b(a.x),f2b(a.y),f2b(a.z),f2b(a.w),
                  f2b(c.x),f2b(c.y),f2b(c.z),f2b(c.w) };
    return *reinterpret_cast<bf16x8*>(o);
}

// ---------------------------------------------------------------------------
// ingest: canonicalize all fp32 params into device globals
#define IN_N0 199680     // Wih0 768*260
#define IN_N1 396288     // + Whh0
#define IN_N2 592896     // + Wih1
#define IN_N3 789504     // + Whh1
#define IN_N4 838656     // + Wcat 96*512
#define IN_N5 841838     // + smalls 3182
__global__ __launch_bounds__(256) void k_ingest(
    const float* __restrict__ Wih0, const float* __restrict__ Whh0,
    const float* __restrict__ Wih1, const float* __restrict__ Whh1,
    const float* __restrict__ Wpi, const float* __restrict__ Wsig,
    const float* __restrict__ Wmu,
    const float* __restrict__ Wpre, const float* __restrict__ bpre,
    const float* __restrict__ bih0, const float* __restrict__ bhh0,
    const float* __restrict__ bih1, const float* __restrict__ bhh1,
    const float* __restrict__ bpi, const float* __restrict__ bsig,
    const float* __restrict__ bmu)
{
    int j = blockIdx.x*256 + threadIdx.x;
    if (j < IN_N0){
        int r = j/260, c = j - r*260;
        float v = Wih0[j];
        if (c < 256) gWmain[r*256 + c] = f2b(v);
        else         gWtail[r*4 + (c-256)] = v;
    } else if (j < IN_N1){
        int k = j - IN_N0; gWHH0[k] = f2b(Whh0[k]);
    } else if (j < IN_N2){
        int k = j - IN_N1; gWIH1[k] = f2b(Wih1[k]);
    } else if (j < IN_N3){
        int k = j - IN_N2; gWHH1[k] = f2b(Whh1[k]);
    } else if (j < IN_N4){
        int k = j - IN_N3; int r = k >> 9, c = k & 511;
        float v = 0.f;
        if      (r < 10) v = Wpi[r*512 + c];
        else if (r < 50) v = Wsig[(r-10)*512 + c];
        else if (r < 90) v = Wmu[(r-50)*512 + c];
        gWcat[k] = f2b(v);
    } else if (j < IN_N5){
        int k = j - IN_N4;
        float v;
        if      (k < 16)   v = Wpre[k];
        else if (k < 20)   v = bpre[k-16];
        else if (k < 788)  v = bih0[k-20];
        else if (k < 1556) v = bhh0[k-788];
        else if (k < 2324) v = bih1[k-1556];
        else if (k < 3092) v = bhh1[k-2324];
        else if (k < 3102) v = bpi[k-3092];
        else if (k < 3142) v = bsig[k-3102];
        else               v = bmu[k-3142];
        gSm[k] = v;
    }
}

// ---------------------------------------------------------------------------
// Fused sequential 2-layer ZoneOut-GRU + MDN projection + heads.
// 32 blocks x 4 batches x 256 threads. bf16 weights from device globals,
// streamed from L2 each step. fp32 state, fp32 outputs.
__global__ __launch_bounds__(256, 1) void k_recur(
    const float* __restrict__ enc, const float* __restrict__ tgt,
    float* __restrict__ dout)
{
    __shared__ bf16  xb[4][264];
    __shared__ bf16  h0b[4][264];
    __shared__ bf16  h1b[4][264];
    __shared__ float h0f[4][256];
    __shared__ float h1f[4][256];
    __shared__ float bufA[3][4][264];
    __shared__ float bufB[3][4][264];
    __shared__ float st[4][100];
    __shared__ float pn[4][4];

    const int tid = threadIdx.x, w = tid>>6, lane = tid&63;
    const int col = lane&15, quad = lane>>4;
    const int bg4 = blockIdx.x*4;

    for (int i=tid; i<4*264; i+=256){
        (&xb[0][0])[i]=f2b(0.f); (&h0b[0][0])[i]=f2b(0.f); (&h1b[0][0])[i]=f2b(0.f);
    }
    for (int i=tid; i<4*256; i+=256){ (&h0f[0][0])[i]=0.f; (&h1f[0][0])[i]=0.f; }
    __syncthreads();

    // 768x4 (K=256) matmul: dst[g][batch][dim] = W[g*256+dim, :] . hb[batch, :]
    auto matblock = [&](const bf16* __restrict__ Wg, const bf16 (&hb)[4][264],
                        float (&dst)[3][4][264]){
        bf16x8 bfr[8];
        const bf16* hrow = &hb[col & 3][0];
        #pragma unroll
        for (int kt=0; kt<8; kt++)
            bfr[kt] = *reinterpret_cast<const bf16x8*>(hrow + kt*32 + quad*8);
        #pragma unroll
        for (int g=0; g<3; g++)
            #pragma unroll
            for (int i=0; i<4; i++){
                f32x4 a2 = {0.f,0.f,0.f,0.f};
                int r0 = g*256 + w*64 + i*16 + col;
                #pragma unroll
                for (int kt=0; kt<8; kt++){
                    bf16x8 av = *reinterpret_cast<const bf16x8*>(Wg + (size_t)r0*256 + kt*32 + quad*8);
                    a2 = mfma16(av, bfr[kt], a2);
                }
                if (col < 4){
                    #pragma unroll
                    for (int r=0; r<4; r++)
                        dst[g][col][w*64 + i*16 + quad*4 + r] = a2[r];
                }
            }
    };

    for (int t=0; t<S_; t++){
        // ---- stage enc(t) (fp32 -> bf16) + prenet ----
        if (tid < 128){
            int b = tid>>5, c8 = tid&31;
            bf16x8 v = cvt8(enc + ((size_t)(bg4+b)*S_ + t)*C_ + c8*8);
            *reinterpret_cast<bf16x8*>(&xb[b][c8*8]) = v;
        } else if (tid < 144){
            int b = (tid-128)>>2, jj = (tid-128)&3;
            float acc = gSm[SM_BPRE + jj];
            if (t){
                const float* pv = tgt + ((size_t)(bg4+b)*S_ + (t-1))*4;
                #pragma unroll
                for (int q=0; q<4; q++)
                    acc += gSm[SM_WPRE + jj*4+q] * pv[q];
            }
            pn[b][jj] = acc;
        }
        __syncthreads();
        // ---- layer-0 matmuls ----
        matblock(gWmain, xb,  bufA);   // gi0 main (K=256 enc part)
        matblock(gWHH0,  h0b, bufB);   // gh0
        __syncthreads();
        // ---- gates layer 0 (wave = batch) ----
        {
            float p0 = pn[w][0], p1 = pn[w][1], p2 = pn[w][2], p3 = pn[w][3];
            #pragma unroll
            for (int k=0; k<4; k++){
                int d = lane + 64*k;
                float4 w0 = ((const float4*)gWtail)[d];
                float4 w1 = ((const float4*)gWtail)[256+d];
                float4 w2 = ((const float4*)gWtail)[512+d];
                float ir  = bufA[0][w][d] + gSm[SM_BIH0+d]     + w0.x*p0+w0.y*p1+w0.z*p2+w0.w*p3;
                float iz  = bufA[1][w][d] + gSm[SM_BIH0+256+d] + w1.x*p0+w1.y*p1+w1.z*p2+w1.w*p3;
                float inn = bufA[2][w][d] + gSm[SM_BIH0+512+d] + w2.x*p0+w2.y*p1+w2.z*p2+w2.w*p3;
                float hr  = bufB[0][w][d] + gSm[SM_BHH0+d];
                float hz  = bufB[1][w][d] + gSm[SM_BHH0+256+d];
                float hn  = bufB[2][w][d] + gSm[SM_BHH0+512+d];
                float r = sigm(ir + hr), z = sigm(iz + hz);
                float n = tanhfast(inn + r*hn);
                float h = h0f[w][d];
                float hp = 0.1f*h + 0.9f*((1.f - z)*n + z*h);
                h0f[w][d] = hp; h0b[w][d] = f2b(hp);
            }
        }
        __syncthreads();
        // ---- layer-1 matmuls ----
        matblock(gWIH1, h0b, bufA);
        matblock(gWHH1, h1b, bufB);
        __syncthreads();
        // ---- gates layer 1 ----
        #pragma unroll
        for (int k=0; k<4; k++){
            int d = lane + 64*k;
            float ir  = bufA[0][w][d] + gSm[SM_BIH1+d];
            float iz  = bufA[1][w][d] + gSm[SM_BIH1+256+d];
            float inn = bufA[2][w][d] + gSm[SM_BIH1+512+d];
            float hr  = bufB[0][w][d] + gSm[SM_BHH1+d];
            float hz  = bufB[1][w][d] + gSm[SM_BHH1+256+d];
            float hn  = bufB[2][w][d] + gSm[SM_BHH1+512+d];
            float r = sigm(ir + hr), z = sigm(iz + hz);
            float n = tanhfast(inn + r*hn);
            float h = h1f[w][d];
            float hp = 0.1f*h + 0.9f*((1.f - z)*n + z*h);
            h1f[w][d] = hp; h1b[w][d] = f2b(hp);
        }
        __syncthreads();
        // ---- fused projection: [Wpi;Wsig;Wmu] @ [h1 | enc] ----
        for (int tile = w; tile < 6; tile += 4){
            int gr = tile*16 + col;
            f32x4 a2 = {0.f,0.f,0.f,0.f};
            #pragma unroll
            for (int kt=0; kt<16; kt++){
                bf16x8 bq = (kt < 8)
                    ? *reinterpret_cast<const bf16x8*>(&h1b[col & 3][kt*32 + quad*8])
                    : *reinterpret_cast<const bf16x8*>(&xb[col & 3][(kt-8)*32 + quad*8]);
                bf16x8 aq = *reinterpret_cast<const bf16x8*>(gWcat + (size_t)gr*512 + kt*32 + quad*8);
                a2 = mfma16(aq, bq, a2);
            }
            if (col < 4){
                #pragma unroll
                for (int r=0; r<4; r++)
                    st[col][tile*16 + quad*4 + r] = a2[r];
            }
        }
        __syncthreads();
        // ---- heads epilogue (one thread per batch), fp32 stores ----
        if (tid < 4){
            const float* v = st[tid];
            const size_t m = (size_t)(bg4 + tid)*S_ + t;
            float x[10], mx = -1e30f;
            #pragma unroll
            for (int g=0; g<10; g++){ x[g] = v[g] + gSm[SM_BPI+g]; mx = fmaxf(mx, x[g]); }
            float sum = 0.f;
            #pragma unroll
            for (int g=0; g<10; g++){ x[g] = __expf(x[g]-mx); sum += x[g]; }
            float inv = 1.f/sum;
            #pragma unroll
            for (int g=0; g<10; g++)
                dout[OFF_PI + m*10 + g] = x[g]*inv;
            #pragma unroll
            for (int i=0; i<40; i++){
                float s = v[10+i] + gSm[SM_BSIG+i];
                dout[OFF_SIG + m*40 + i] = (s > 0.f) ? (s + 1.f) : __expf(s);
            }
            #pragma unroll
            for (int i=0; i<40; i++)
                dout[OFF_MU + m*40 + i] = v[50+i] + gSm[SM_BMU+i];
        }
        __syncthreads();
    }
}

// ---------------------------------------------------------------------------
// blocks 0..255: outs = fp32 copy of tgt; blocks 256..383: mask
__global__ __launch_bounds__(256) void k_misc(const float* __restrict__ tgt,
    const int* __restrict__ dur, float* __restrict__ dout)
{
    if (blockIdx.x < 256){
        int i = blockIdx.x*256 + threadIdx.x;        // 65536 float4 = 262144 floats
        ((float4*)dout)[i] = ((const float4*)tgt)[i];
    } else {
        __shared__ int red[256];
        int b = blockIdx.x - 256;
        int c = 0;
        for (int s = threadIdx.x; s < S_; s += 256) c += (dur[b*S_ + s] > 0) ? 1 : 0;
        red[threadIdx.x] = c;
        __syncthreads();
        for (int off=128; off>0; off>>=1){
            if (threadIdx.x < off) red[threadIdx.x] += red[threadIdx.x+off];
            __syncthreads();
        }
        int snt = red[0];
        for (int s = threadIdx.x; s < S_; s += 256)
            dout[OFF_MASK + (size_t)b*S_ + s] = (s >= snt) ? 1.f : 0.f;
    }
}

// ---------------------------------------------------------------------------
extern "C" void kernel_launch(void* const* d_in, const int* in_sizes, int n_in,
                              void* d_out, int out_size, void* d_ws, size_t ws_size,
                              hipStream_t stream)
{
    (void)d_ws; (void)ws_size;  // deliberately unused (device-global staging)
    const float* enc  = (const float*)d_in[0];
    const float* tgt  = (const float*)d_in[1];
    const int*   dur  = (const int*)  d_in[2];
    const float* Wpre = (const float*)d_in[3];
    const float* bpre = (const float*)d_in[4];
    const float* Wih0 = (const float*)d_in[5];
    const float* Whh0 = (const float*)d_in[6];
    const float* bih0 = (const float*)d_in[7];
    const float* bhh0 = (const float*)d_in[8];
    const float* Wih1 = (const float*)d_in[9];
    const float* Whh1 = (const float*)d_in[10];
    const float* bih1 = (const float*)d_in[11];
    const float* bhh1 = (const float*)d_in[12];
    const float* Wpi  = (const float*)d_in[13];
    const float* bpi  = (const float*)d_in[14];
    const float* Wsig = (const float*)d_in[15];
    const float* bsig = (const float*)d_in[16];
    const float* Wmu  = (const float*)d_in[17];
    const float* bmu  = (const float*)d_in[18];
    float* dout = (float*)d_out;

    hipLaunchKernelGGL(k_ingest, dim3(3289), dim3(256), 0, stream,
                       Wih0, Whh0, Wih1, Whh1, Wpi, Wsig, Wmu,
                       Wpre, bpre, bih0, bhh0, bih1, bhh1, bpi, bsig, bmu);
    hipLaunchKernelGGL(k_recur, dim3(32), dim3(256), 0, stream, enc, tgt, dout);
    hipLaunchKernelGGL(k_misc,  dim3(384), dim3(256), 0, stream, tgt, dur, dout);
}

// Round 8
// 22428.989 us; speedup vs baseline: 1.2061x; 1.2061x over previous
//
#include <hip/hip_runtime.h>
#include <hip/hip_bf16.h>
#include <stdint.h>

#define B_   128
#define S_   512
#define C_   256
#define DG_  256

// d_out offsets (fp32 elements): outs, pi, sigma, mu, mask
#define OFF_PI   262144
#define OFF_SIG  917504
#define OFF_MU   3538944
#define OFF_MASK 6160384

typedef __hip_bfloat16 bf16;
typedef __bf16 bf16x8 __attribute__((ext_vector_type(8)));
typedef float  f32x4  __attribute__((ext_vector_type(4)));

// ---- staging in device globals (zero d_ws dependence) ----
__device__ __align__(16) bf16  gWmain[768*256];   // Wih0[:, :256]
__device__ __align__(16) bf16  gWHH0 [768*256];
__device__ __align__(16) bf16  gWIH1 [768*256];
__device__ __align__(16) bf16  gWHH1 [768*256];
__device__ __align__(16) bf16  gWcat [96*512];    // [W_pi; W_sigma; W_mu; 0]
__device__ __align__(16) float gWtail[768*4];     // Wih0[:, 256:260] fp32
__device__ __align__(16) float gSm   [3200];      // small params fp32
__device__ __align__(16) bf16  gHbuf [B_*S_*DG_]; // h1 per (b,t)  (32 MB)

// gSm offsets
#define SM_WPRE 0
#define SM_BPRE 16
#define SM_BIH0 20
#define SM_BHH0 788
#define SM_BIH1 1556
#define SM_BHH1 2324
#define SM_BPI  3092
#define SM_BSIG 3102
#define SM_BMU  3142

__device__ __forceinline__ bf16  f2b(float x){ return __float2bfloat16(x); }
__device__ __forceinline__ float sigm(float x){ return 1.f/(1.f + __expf(-x)); }
__device__ __forceinline__ float tanhfast(float x){ return 1.f - 2.f/(__expf(2.f*x) + 1.f); }
__device__ __forceinline__ f32x4 mfma16(bf16x8 a, bf16x8 b, f32x4 c){
    return __builtin_amdgcn_mfma_f32_16x16x32_bf16(a, b, c, 0, 0, 0);
}
__device__ __forceinline__ bf16x8 cvt8(const float* f){
    float4 a = *reinterpret_cast<const float4*>(f);
    float4 c = *reinterpret_cast<const float4*>(f + 4);
    bf16 o[8] = { f2b(a.x),f2b(a.y),f2b(a.z),f2b(a.w),
                  f2b(c.x),f2b(c.y),f2b(c.z),f2b(c.w) };
    return *reinterpret_cast<bf16x8*>(o);
}

// ---------------------------------------------------------------------------
// ingest: canonicalize fp32 params into device globals
#define IN_N0 199680
#define IN_N1 396288
#define IN_N2 592896
#define IN_N3 789504
#define IN_N4 838656
#define IN_N5 841838
__global__ __launch_bounds__(256) void k_ingest(
    const float* __restrict__ Wih0, const float* __restrict__ Whh0,
    const float* __restrict__ Wih1, const float* __restrict__ Whh1,
    const float* __restrict__ Wpi, const float* __restrict__ Wsig,
    const float* __restrict__ Wmu,
    const float* __restrict__ Wpre, const float* __restrict__ bpre,
    const float* __restrict__ bih0, const float* __restrict__ bhh0,
    const float* __restrict__ bih1, const float* __restrict__ bhh1,
    const float* __restrict__ bpi, const float* __restrict__ bsig,
    const float* __restrict__ bmu)
{
    int j = blockIdx.x*256 + threadIdx.x;
    if (j < IN_N0){
        int r = j/260, c = j - r*260;
        float v = Wih0[j];
        if (c < 256) gWmain[r*256 + c] = f2b(v);
        else         gWtail[r*4 + (c-256)] = v;
    } else if (j < IN_N1){
        int k = j - IN_N0; gWHH0[k] = f2b(Whh0[k]);
    } else if (j < IN_N2){
        int k = j - IN_N1; gWIH1[k] = f2b(Wih1[k]);
    } else if (j < IN_N3){
        int k = j - IN_N2; gWHH1[k] = f2b(Whh1[k]);
    } else if (j < IN_N4){
        int k = j - IN_N3; int r = k >> 9, c = k & 511;
        float v = 0.f;
        if      (r < 10) v = Wpi[r*512 + c];
        else if (r < 50) v = Wsig[(r-10)*512 + c];
        else if (r < 90) v = Wmu[(r-50)*512 + c];
        gWcat[k] = f2b(v);
    } else if (j < IN_N5){
        int k = j - IN_N4;
        float v;
        if      (k < 16)   v = Wpre[k];
        else if (k < 20)   v = bpre[k-16];
        else if (k < 788)  v = bih0[k-20];
        else if (k < 1556) v = bhh0[k-788];
        else if (k < 2324) v = bih1[k-1556];
        else if (k < 3092) v = bhh1[k-2324];
        else if (k < 3102) v = bpi[k-3092];
        else if (k < 3142) v = bsig[k-3102];
        else               v = bmu[k-3142];
        gSm[k] = v;
    }
}

// ---------------------------------------------------------------------------
// Sequential 2-layer ZoneOut-GRU. 32 blocks x 4 batches x 1024 threads
// (16 waves; 4 waves/SIMD for latency hiding). Per phase, the two 768x256
// GEMVs are split into 96 row-tiles, 6 per wave. Writes h1 to gHbuf.
__global__ __launch_bounds__(1024, 4) void k_recur(
    const float* __restrict__ enc, const float* __restrict__ tgt)
{
    __shared__ bf16  xb[4][264];
    __shared__ bf16  h0b[4][264];
    __shared__ bf16  h1b[4][264];
    __shared__ float h0f[4][256];
    __shared__ float h1f[4][256];
    __shared__ float bufA[3][4][264];
    __shared__ float bufB[3][4][264];
    __shared__ float pn[4][4];

    const int tid = threadIdx.x, w = tid>>6, lane = tid&63;
    const int col = lane&15, quad = lane>>4;
    const int bg4 = blockIdx.x*4;

    for (int i=tid; i<4*264; i+=1024){ (&h0b[0][0])[i]=f2b(0.f); (&h1b[0][0])[i]=f2b(0.f); }
    for (int i=tid; i<4*256; i+=1024){ (&h0f[0][0])[i]=0.f; (&h1f[0][0])[i]=0.f; }
    __syncthreads();

    // dual matblock phase: waves 0-7 -> WA@hbA -> bufA ; waves 8-15 -> WB@hbB -> bufB
    auto dual = [&](const bf16* __restrict__ WA, const bf16 (&hbA)[4][264],
                    const bf16* __restrict__ WB, const bf16 (&hbB)[4][264]){
        const int side = w >> 3;
        const bf16* __restrict__ Wg = side ? WB : WA;
        const bf16* hrow = side ? &hbB[col & 3][0] : &hbA[col & 3][0];
        float (*dst)[4][264] = side ? bufB : bufA;
        bf16x8 bfr[8];
        #pragma unroll
        for (int kt=0; kt<8; kt++)
            bfr[kt] = *reinterpret_cast<const bf16x8*>(hrow + kt*32 + quad*8);
        #pragma unroll 2
        for (int j=0; j<6; j++){
            int v = (w & 7)*6 + j;           // 0..47 row-tiles
            int g = v >> 4, q = v & 15;
            int r0 = g*256 + q*16 + col;
            f32x4 a2 = {0.f,0.f,0.f,0.f};
            #pragma unroll
            for (int kt=0; kt<8; kt++){
                bf16x8 av = *reinterpret_cast<const bf16x8*>(Wg + (size_t)r0*256 + kt*32 + quad*8);
                a2 = mfma16(av, bfr[kt], a2);
            }
            if (col < 4){
                #pragma unroll
                for (int r=0; r<4; r++)
                    dst[g][col][q*16 + quad*4 + r] = a2[r];
            }
        }
    };

    for (int t=0; t<S_; t++){
        // ---- stage enc(t) fp32->bf16 + prenet ----
        if (tid < 128){
            int b = tid>>5, c8 = tid&31;
            *reinterpret_cast<bf16x8*>(&xb[b][c8*8]) =
                cvt8(enc + ((size_t)(bg4+b)*S_ + t)*C_ + c8*8);
        } else if (tid < 144){
            int b = (tid-128)>>2, jj = (tid-128)&3;
            float acc = gSm[SM_BPRE + jj];
            if (t){
                const float* pv = tgt + ((size_t)(bg4+b)*S_ + (t-1))*4;
                #pragma unroll
                for (int q=0; q<4; q++) acc += gSm[SM_WPRE + jj*4+q] * pv[q];
            }
            pn[b][jj] = acc;
        }
        __syncthreads();
        // ---- phase A: gi0 = Wmain@xb -> bufA ; gh0 = WHH0@h0b -> bufB ----
        dual(gWmain, xb, gWHH0, h0b);
        __syncthreads();
        // ---- gates layer 0: exactly one (batch, dim) per thread ----
        {
            int b = tid >> 8, d = tid & 255;
            float p0 = pn[b][0], p1 = pn[b][1], p2 = pn[b][2], p3 = pn[b][3];
            float4 w0 = ((const float4*)gWtail)[d];
            float4 w1 = ((const float4*)gWtail)[256+d];
            float4 w2 = ((const float4*)gWtail)[512+d];
            float ir  = bufA[0][b][d] + gSm[SM_BIH0+d]     + w0.x*p0+w0.y*p1+w0.z*p2+w0.w*p3;
            float iz  = bufA[1][b][d] + gSm[SM_BIH0+256+d] + w1.x*p0+w1.y*p1+w1.z*p2+w1.w*p3;
            float inn = bufA[2][b][d] + gSm[SM_BIH0+512+d] + w2.x*p0+w2.y*p1+w2.z*p2+w2.w*p3;
            float hr  = bufB[0][b][d] + gSm[SM_BHH0+d];
            float hz  = bufB[1][b][d] + gSm[SM_BHH0+256+d];
            float hn  = bufB[2][b][d] + gSm[SM_BHH0+512+d];
            float r = sigm(ir + hr), z = sigm(iz + hz);
            float n = tanhfast(inn + r*hn);
            float h = h0f[b][d];
            float hp = 0.1f*h + 0.9f*((1.f - z)*n + z*h);
            h0f[b][d] = hp; h0b[b][d] = f2b(hp);
        }
        __syncthreads();
        // ---- phase B: gi1 = WIH1@h0b' -> bufA ; gh1 = WHH1@h1b -> bufB ----
        dual(gWIH1, h0b, gWHH1, h1b);
        __syncthreads();
        // ---- gates layer 1 + H write ----
        {
            int b = tid >> 8, d = tid & 255;
            float ir  = bufA[0][b][d] + gSm[SM_BIH1+d];
            float iz  = bufA[1][b][d] + gSm[SM_BIH1+256+d];
            float inn = bufA[2][b][d] + gSm[SM_BIH1+512+d];
            float hr  = bufB[0][b][d] + gSm[SM_BHH1+d];
            float hz  = bufB[1][b][d] + gSm[SM_BHH1+256+d];
            float hn  = bufB[2][b][d] + gSm[SM_BHH1+512+d];
            float r = sigm(ir + hr), z = sigm(iz + hz);
            float n = tanhfast(inn + r*hn);
            float h = h1f[b][d];
            float hp = 0.1f*h + 0.9f*((1.f - z)*n + z*h);
            h1f[b][d] = hp; h1b[b][d] = f2b(hp);
            gHbuf[((size_t)(bg4+b)*S_ + t)*DG_ + d] = f2b(hp);
        }
        __syncthreads();
    }
}

// ---------------------------------------------------------------------------
// Fused projection + heads: 512 blocks x 128 rows. [H|enc]@Wcat^T -> LDS ->
// softmax/elu/mu, fp32 stores.
__global__ __launch_bounds__(256) void k_proj(
    const float* __restrict__ enc, float* __restrict__ dout)
{
    __shared__ float st[128][100];
    const int tid = threadIdx.x, w = tid>>6, lane = tid&63;
    const int col = lane&15, quad = lane>>4;
    const int Mb = blockIdx.x*128;
    const int M0 = Mb + w*32;

    f32x4 acc[2][6];
    #pragma unroll
    for (int mt=0; mt<2; mt++)
        #pragma unroll
        for (int nt=0; nt<6; nt++) acc[mt][nt] = f32x4{0.f,0.f,0.f,0.f};

    #pragma unroll
    for (int kt=0; kt<16; kt++){
        bf16x8 a0, a1;
        if (kt < 8){
            a0 = *reinterpret_cast<const bf16x8*>(gHbuf + (size_t)(M0 +      col)*DG_ + kt*32 + quad*8);
            a1 = *reinterpret_cast<const bf16x8*>(gHbuf + (size_t)(M0 + 16 + col)*DG_ + kt*32 + quad*8);
        } else {
            a0 = cvt8(enc + (size_t)(M0 +      col)*C_ + (kt-8)*32 + quad*8);
            a1 = cvt8(enc + (size_t)(M0 + 16 + col)*C_ + (kt-8)*32 + quad*8);
        }
        #pragma unroll
        for (int nt=0; nt<6; nt++){
            bf16x8 b = *reinterpret_cast<const bf16x8*>(gWcat + (size_t)(nt*16 + col)*512 + kt*32 + quad*8);
            acc[0][nt] = mfma16(a0, b, acc[0][nt]);
            acc[1][nt] = mfma16(a1, b, acc[1][nt]);
        }
    }
    #pragma unroll
    for (int nt=0; nt<6; nt++)
        #pragma unroll
        for (int mt=0; mt<2; mt++)
            #pragma unroll
            for (int r=0; r<4; r++)
                st[w*32 + mt*16 + quad*4 + r][nt*16 + col] = acc[mt][nt][r];
    __syncthreads();

    if (tid < 128){
        const float* v = st[tid];
        const size_t m = (size_t)Mb + tid;
        float x[10], mx = -1e30f;
        #pragma unroll
        for (int g=0; g<10; g++){ x[g] = v[g] + gSm[SM_BPI+g]; mx = fmaxf(mx, x[g]); }
        float sum = 0.f;
        #pragma unroll
        for (int g=0; g<10; g++){ x[g] = __expf(x[g]-mx); sum += x[g]; }
        float inv = 1.f/sum;
        #pragma unroll
        for (int g=0; g<10; g++)
            dout[OFF_PI + m*10 + g] = x[g]*inv;
        #pragma unroll
        for (int i=0; i<40; i++){
            float s = v[10+i] + gSm[SM_BSIG+i];
            dout[OFF_SIG + m*40 + i] = (s > 0.f) ? (s + 1.f) : __expf(s);
        }
        #pragma unroll
        for (int i=0; i<40; i++)
            dout[OFF_MU + m*40 + i] = v[50+i] + gSm[SM_BMU+i];
    }
}

// ---------------------------------------------------------------------------
// blocks 0..255: outs = fp32 copy of tgt; blocks 256..383: mask
__global__ __launch_bounds__(256) void k_misc(const float* __restrict__ tgt,
    const int* __restrict__ dur, float* __restrict__ dout)
{
    if (blockIdx.x < 256){
        int i = blockIdx.x*256 + threadIdx.x;
        ((float4*)dout)[i] = ((const float4*)tgt)[i];
    } else {
        __shared__ int red[256];
        int b = blockIdx.x - 256;
        int c = 0;
        for (int s = threadIdx.x; s < S_; s += 256) c += (dur[b*S_ + s] > 0) ? 1 : 0;
        red[threadIdx.x] = c;
        __syncthreads();
        for (int off=128; off>0; off>>=1){
            if (threadIdx.x < off) red[threadIdx.x] += red[threadIdx.x+off];
            __syncthreads();
        }
        int snt = red[0];
        for (int s = threadIdx.x; s < S_; s += 256)
            dout[OFF_MASK + (size_t)b*S_ + s] = (s >= snt) ? 1.f : 0.f;
    }
}

// ---------------------------------------------------------------------------
extern "C" void kernel_launch(void* const* d_in, const int* in_sizes, int n_in,
                              void* d_out, int out_size, void* d_ws, size_t ws_size,
                              hipStream_t stream)
{
    (void)d_ws; (void)ws_size;
    const float* enc  = (const float*)d_in[0];
    const float* tgt  = (const float*)d_in[1];
    const int*   dur  = (const int*)  d_in[2];
    const float* Wpre = (const float*)d_in[3];
    const float* bpre = (const float*)d_in[4];
    const float* Wih0 = (const float*)d_in[5];
    const float* Whh0 = (const float*)d_in[6];
    const float* bih0 = (const float*)d_in[7];
    const float* bhh0 = (const float*)d_in[8];
    const float* Wih1 = (const float*)d_in[9];
    const float* Whh1 = (const float*)d_in[10];
    const float* bih1 = (const float*)d_in[11];
    const float* bhh1 = (const float*)d_in[12];
    const float* Wpi  = (const float*)d_in[13];
    const float* bpi  = (const float*)d_in[14];
    const float* Wsig = (const float*)d_in[15];
    const float* bsig = (const float*)d_in[16];
    const float* Wmu  = (const float*)d_in[17];
    const float* bmu  = (const float*)d_in[18];
    float* dout = (float*)d_out;

    hipLaunchKernelGGL(k_ingest, dim3(3289), dim3(256), 0, stream,
                       Wih0, Whh0, Wih1, Whh1, Wpi, Wsig, Wmu,
                       Wpre, bpre, bih0, bhh0, bih1, bhh1, bpi, bsig, bmu);
    hipLaunchKernelGGL(k_recur, dim3(32),  dim3(1024), 0, stream, enc, tgt);
    hipLaunchKernelGGL(k_proj,  dim3(512), dim3(256),  0, stream, enc, dout);
    hipLaunchKernelGGL(k_misc,  dim3(384), dim3(256),  0, stream, tgt, dur, dout);
}